// Round 2
// baseline (221.633 us; speedup 1.0000x reference)
//
#include <hip/hip_runtime.h>

typedef _Float16 f16;
typedef _Float16 f16x2 __attribute__((ext_vector_type(2)));
typedef _Float16 f16x8 __attribute__((ext_vector_type(8)));
typedef float    f32x4 __attribute__((ext_vector_type(4)));

#define DIM 128

// silu(x) = x / (1 + e^-x); v_exp_f32 computes 2^x -> scale by log2(e).
__device__ __forceinline__ float silu_f(float x) {
    float e = __builtin_amdgcn_exp2f(x * -1.44269504088896341f);
    return x * __builtin_amdgcn_rcpf(1.0f + e);
}

// Block = 256 threads = 4 waves; block tile = 64 rows.
// Wave wv owns output cols [32wv, 32wv+32) for ALL 64 rows -> W1/W2 frags live
// in REGISTERS (8+8 f16x8 = 64 VGPRs), loaded from global once per block.
// LDS: emb A-frag exchange (16KB) + x1 xor-swizzled staging (16KB) = 32KB.
__global__ __launch_bounds__(256, 3)
void ts_mlp_kernel(const float* __restrict__ t,
                   const float* __restrict__ W1, const float* __restrict__ b1,
                   const float* __restrict__ W2, const float* __restrict__ b2,
                   float* __restrict__ out, int B) {
    __shared__ f16x8 embf[4][4][64];   // [m-tile][kt][lane] A-frags, 16KB
    __shared__ f16x2 x1s[1024][4];     // 64 rows x 16 chunks of 16B, swizzled, 16KB

    const int tid  = threadIdx.x;
    const int wv   = tid >> 6;
    const int lane = tid & 63;
    const int q    = lane >> 4;   // quad 0..3
    const int ln   = lane & 15;
    const int par  = lane & 1;

    const int ntiles = B >> 6;

    // ---- prefetch t for this block's 4 tiles (hide global latency)
    float t4[4];
#pragma unroll
    for (int ti = 0; ti < 4; ++ti) {
        const int tile = blockIdx.x * 4 + ti;
        t4[ti] = (tile < ntiles) ? t[tile * 64 + wv * 16 + ln] : 0.0f;
    }

    // ---- weights -> registers in mfma_f32_16x16x32_f16 B-frag layout.
    // Frag (kt,u), lane: B[k][n] with n = 32wv+16u+ln, k = 32kt+8q+j  (= W[n][k])
    f16x8 w1f[4][2], w2f[4][2];
    float b1v[2], b2v[2];
#pragma unroll
    for (int u = 0; u < 2; ++u) {
        const int n = wv * 32 + u * 16 + ln;
        b1v[u] = b1[n];
        b2v[u] = b2[n];
#pragma unroll
        for (int kt = 0; kt < 4; ++kt) {
            const float4* p1 = (const float4*)(W1 + n * DIM + kt * 32 + q * 8);
            const float4* p2 = (const float4*)(W2 + n * DIM + kt * 32 + q * 8);
            const float4 a = p1[0], b = p1[1], c = p2[0], d = p2[1];
            f16x8 f1, f2;
            f1[0]=(f16)a.x; f1[1]=(f16)a.y; f1[2]=(f16)a.z; f1[3]=(f16)a.w;
            f1[4]=(f16)b.x; f1[5]=(f16)b.y; f1[6]=(f16)b.z; f1[7]=(f16)b.w;
            f2[0]=(f16)c.x; f2[1]=(f16)c.y; f2[2]=(f16)c.z; f2[3]=(f16)c.w;
            f2[4]=(f16)d.x; f2[5]=(f16)d.y; f2[6]=(f16)d.z; f2[7]=(f16)d.w;
            w1f[kt][u] = f1;
            w2f[kt][u] = f2;
        }
    }

#pragma unroll 1
    for (int ti = 0; ti < 4; ++ti) {
        const int tile = blockIdx.x * 4 + ti;
        if (tile >= ntiles) break;
        const int row0 = tile * 64;

        // ---- emb for this wave's 16 rows, directly in A-frag layout:
        // row m = ln, k = 32kt + 8q + j. v_sin/v_cos take REVOLUTIONS:
        // phase*t [rad] = d*pi*t/128 -> rev = d*t/256.
        const float tv   = t4[ti];
        const float t256 = tv * 0.00390625f;
        const float o256 = (1.0f - tv) * 0.00390625f;
        const float qb   = (float)(q * 8);
#pragma unroll
        for (int kt = 0; kt < 4; ++kt) {
            f16x8 ef;
#pragma unroll
            for (int j = 0; j < 8; ++j) {
                const float fd = (float)(kt * 32 + j) + qb;
                const float c  = __builtin_amdgcn_cosf(fd * t256);
                const float s  = __builtin_amdgcn_sinf(fd * o256);
                ef[j] = (f16)(tv * (c + s));
            }
            embf[wv][kt][lane] = ef;   // b128, conflict-free
        }
        __syncthreads();

        // ---- layer 1: 4 m-tiles x 4 kt x 2 u = 32 MFMAs, W1 from registers
        f32x4 acc[4][2];
#pragma unroll
        for (int mt = 0; mt < 4; ++mt) {
            acc[mt][0] = (f32x4){0.f,0.f,0.f,0.f};
            acc[mt][1] = (f32x4){0.f,0.f,0.f,0.f};
#pragma unroll
            for (int kt = 0; kt < 4; ++kt) {
                const f16x8 af = embf[mt][kt][lane];
                acc[mt][0] = __builtin_amdgcn_mfma_f32_16x16x32_f16(af, w1f[kt][0], acc[mt][0], 0, 0, 0);
                acc[mt][1] = __builtin_amdgcn_mfma_f32_16x16x32_f16(af, w1f[kt][1], acc[mt][1], 0, 0, 0);
            }
        }

        // ---- epilogue 1: bias+silu, pair-pack cross-lane, write x1 (fp16) to LDS.
        // C layout: value r in lane = x1[row = mt*16 + q*4 + r][col = 32wv+16u+ln]
#pragma unroll
        for (int mt = 0; mt < 4; ++mt) {
#pragma unroll
            for (int u = 0; u < 2; ++u) {
                float v[4], pv[4];
#pragma unroll
                for (int r = 0; r < 4; ++r) v[r] = silu_f(acc[mt][u][r] + b1v[u]);
#pragma unroll
                for (int r = 0; r < 4; ++r) pv[r] = __shfl_xor(v[r], 1, 64);
                const int k0  = wv * 32 + u * 16 + (ln & 14); // even col of pair
                const int cch = k0 >> 3;                       // 16B chunk 0..15
                const int hw  = (k0 & 7) >> 1;                 // dword in chunk
#pragma unroll
                for (int p = 0; p < 2; ++p) {
                    const int r = par * 2 + p;   // even lanes rows 0,1; odd rows 2,3
                    const int m = mt * 16 + q * 4 + r;
                    const float lo = par ? pv[r] : v[r];
                    const float hi = par ? v[r] : pv[r];
                    f16x2 h; h.x = (f16)lo; h.y = (f16)hi;
                    x1s[m * 16 + (cch ^ (m & 15))][hw] = h;
                }
            }
        }
        __syncthreads();

        // ---- layer 2 + epilogue 2, per m-tile (short register liveness)
#pragma unroll
        for (int mt = 0; mt < 4; ++mt) {
            f32x4 a2c[2];
            a2c[0] = (f32x4){0.f,0.f,0.f,0.f};
            a2c[1] = (f32x4){0.f,0.f,0.f,0.f};
#pragma unroll
            for (int kt = 0; kt < 4; ++kt) {
                const int m = mt * 16 + ln;
                const f16x8 a2 = *(const f16x8*)&x1s[m * 16 + ((kt * 4 + q) ^ ln)][0];
                a2c[0] = __builtin_amdgcn_mfma_f32_16x16x32_f16(a2, w2f[kt][0], a2c[0], 0, 0, 0);
                a2c[1] = __builtin_amdgcn_mfma_f32_16x16x32_f16(a2, w2f[kt][1], a2c[1], 0, 0, 0);
            }
#pragma unroll
            for (int u = 0; u < 2; ++u) {
                const int col = wv * 32 + u * 16 + ln;
                const size_t rbase = (size_t)(row0 + mt * 16 + q * 4) * DIM + col;
#pragma unroll
                for (int r = 0; r < 4; ++r) {
                    out[rbase + (size_t)r * DIM] = silu_f(a2c[u][r] + b2v[u]);
                }
            }
        }
        __syncthreads();   // protect embf + x1s before next tile overwrites
    }
}

extern "C" void kernel_launch(void* const* d_in, const int* in_sizes, int n_in,
                              void* d_out, int out_size, void* d_ws, size_t ws_size,
                              hipStream_t stream) {
    const float* t  = (const float*)d_in[0];
    const float* W1 = (const float*)d_in[1];
    const float* b1 = (const float*)d_in[2];
    const float* W2 = (const float*)d_in[3];
    const float* b2 = (const float*)d_in[4];
    float* out = (float*)d_out;
    const int B = in_sizes[0];
    const int ntiles = B >> 6;            // 64 rows per tile
    const int grid = (ntiles + 3) >> 2;   // 4 tiles per block
    ts_mlp_kernel<<<dim3(grid), dim3(256), 0, stream>>>(t, W1, b1, W2, b2, out, B);
}